// Round 5
// baseline (173.701 us; speedup 1.0000x reference)
//
#include <hip/hip_runtime.h>

#define HH 512        // sinogram height (H_IN)
#define WW 360        // angles (W_IN)
#define NB 4          // batch
#define DD 512        // output D

// ws layout in floats
#define OFF_TAB  0                          // float2 tab[360] -> 720 floats, pad to 1024
#define OFF_RT   1024                       // radonT [4][360][512] fp32
#define OFF_FILT (1024 + NB*WW*HH)          // filt4 [360][512][4] fp32 (float4 per y)

#define PAD    128
#define SLOT   640                          // 128 pad + 512 data
#define BUFROWS 1408                        // pad|data0|gap|data1|pad (float4 rows)

#define GLOAD_LDS16(gp, lp)                                                   \
    __builtin_amdgcn_global_load_lds(                                         \
        (const __attribute__((address_space(1))) void*)(gp),                  \
        (__attribute__((address_space(3))) void*)(lp), 16, 0, 0)

// ---------------- K0: transpose radon[n][h][w] -> radonT[n][w][h] ----------------
__global__ __launch_bounds__(256) void k_transpose(const float* __restrict__ radon,
                                                   float* __restrict__ ws) {
    __shared__ float tile[32][33];
    int n  = blockIdx.z;
    int w0 = blockIdx.x * 32, h0 = blockIdx.y * 32;
    int x = threadIdx.x, y = threadIdx.y;  // 32 x 8
    const float* rn = radon + n * (HH * WW);
#pragma unroll
    for (int r = 0; r < 32; r += 8) {
        int h = h0 + y + r, w = w0 + x;
        tile[y + r][x] = (w < WW) ? rn[h * WW + w] : 0.f;
    }
    __syncthreads();
    float* rt = ws + OFF_RT + n * (WW * HH);
#pragma unroll
    for (int r = 0; r < 32; r += 8) {
        int w = w0 + y + r, h = h0 + x;
        if (w < WW) rt[w * HH + h] = tile[x][y + r];
    }
}

// ---------------- K1: circular ramp filter (fp32 out) + fused angle table ----------------
// filt4[w][y][n] = sum_d radonT[n][w][(257+y+d)&511] * hG[d]
__global__ __launch_bounds__(256) void k_filter(const float* __restrict__ hG,
                                                float* __restrict__ ws) {
    __shared__ float r2[NB][1024];          // r2[n][i] = col[(i+257)&511]
    int wA  = blockIdx.x;
    int tid = threadIdx.x;

    if (tid == 0) {                          // angle table, double trig (validated R2 path)
        double th = (3.14159265358979323846 / 180.0) * (0.5 * (double)wA);
        double c = cos(th), s = sin(th);
        float2 ab;
        ab.x = (float)(c * (255.5 / 256.0));
        ab.y = (float)(-s * (255.5 / 256.0));
        ((float2*)(ws + OFF_TAB))[wA] = ab;
    }

    const float* rt = ws + OFF_RT;
    for (int t = tid; t < NB * 1024; t += 256) {
        int n = t >> 10, i = t & 1023;
        r2[n][i] = rt[(n * WW + wA) * HH + ((i + 257) & 511)];
    }
    __syncthreads();

    int n = tid >> 6, lane = tid & 63, y0 = lane << 3;   // 8 consecutive y per thread
    float acc[8] = {0, 0, 0, 0, 0, 0, 0, 0};
    const float* rr = &r2[n][y0];
    float4 Wr0 = *(const float4*)(rr + 0);
    float4 Wr1 = *(const float4*)(rr + 4);
    float4 Wr2 = *(const float4*)(rr + 8);
    float4 Wr3 = *(const float4*)(rr + 12);

    for (int d = 0; d < 512; d += 8) {
        float hg[8];
#pragma unroll
        for (int q = 0; q < 8; ++q) hg[q] = hG[d + q];   // uniform -> s_load
        float wf[16] = {Wr0.x, Wr0.y, Wr0.z, Wr0.w, Wr1.x, Wr1.y, Wr1.z, Wr1.w,
                        Wr2.x, Wr2.y, Wr2.z, Wr2.w, Wr3.x, Wr3.y, Wr3.z, Wr3.w};
#pragma unroll
        for (int du = 0; du < 8; ++du)
#pragma unroll
            for (int u = 0; u < 8; ++u)
                acc[u] = fmaf(wf[du + u], hg[du], acc[u]);
        if (d < 504) {
            Wr0 = Wr2; Wr1 = Wr3;
            Wr2 = *(const float4*)(rr + d + 16);
            Wr3 = *(const float4*)(rr + d + 20);
        }
    }
    float* filt = ws + OFF_FILT;
#pragma unroll
    for (int u = 0; u < 8; ++u)
        filt[(wA * HH + y0 + u) * NB + n] = acc[u];
}

// ---------------- K2: backprojection, all 360 angles, direct output ----------------
// LDS buffer: rows [0,128)=0 | [128,640)=angle a0 | [640,768)=0 (shared pad) |
//             [768,1280)=angle a1 | [1280,1408)=0.  py+PAD in [22,745] per slot.
__global__ __launch_bounds__(256) void k_backproj(const float* __restrict__ ws,
                                                  float* __restrict__ out) {
    __shared__ float4 cols[2][BUFROWS];
    const int tid  = threadIdx.x;
    const int lane = tid & 63;
    const int ithr = tid >> 6;                      // 0..3
    const int j    = blockIdx.x * 64 + lane;
    const int i0   = blockIdx.y * 8 + ithr;         // i = i0 + 4u, u<2

    // zero the 3 pad regions of both buffers (never touched by DMA)
    {
        float4 z = make_float4(0.f, 0.f, 0.f, 0.f);
        for (int q = tid; q < 768; q += 256) {
            int b = q / 384, r = q - b * 384;
            int row = (r < 128) ? r : ((r < 256) ? 512 + r : 1024 + r);
            cols[b][row] = z;
        }
    }

    const float2* tab = (const float2*)(ws + OFF_TAB);
    const float4* fd  = (const float4*)(ws + OFF_FILT);

    float acc[2][4];
#pragma unroll
    for (int u = 0; u < 2; ++u)
#pragma unroll
        for (int n = 0; n < 4; ++n) acc[u][n] = 0.f;

    float jf = (float)(j - 256);
    float ifl[2];
#pragma unroll
    for (int u = 0; u < 2; ++u) ifl[u] = (float)(i0 + 4 * u - 256);

    // prologue: stage angles 0,1 into buf 0 (two contiguous 512-row regions)
    {
        const float4* src = fd;                     // angles 0,1 = 1024 contiguous float4
#pragma unroll
        for (int c = 0; c < 2; ++c) {
            int idx = tid + c * 256;
            GLOAD_LDS16(src + idx,       &cols[0][PAD + idx]);
            GLOAD_LDS16(src + 512 + idx, &cols[0][768 + idx]);
        }
    }
    __syncthreads();   // drains vmcnt(0): DMA + pad writes visible

    int cur = 0;
    for (int t = 0; t < 180; ++t) {
        if (t + 1 < 180) {                          // stage next 2 angles into other buf
            const float4* src = fd + (size_t)(2 * t + 2) * 512;
            float4* d0 = &cols[cur ^ 1][PAD];
            float4* d1 = &cols[cur ^ 1][768];
#pragma unroll
            for (int c = 0; c < 2; ++c) {
                int idx = tid + c * 256;
                GLOAD_LDS16(src + idx,       d0 + idx);
                GLOAD_LDS16(src + 512 + idx, d1 + idx);
            }
        }

#pragma unroll
        for (int a = 0; a < 2; ++a) {
            float2 ab = tab[2 * t + a];
            const float4* cb = &cols[cur][a * SLOT];
            float pybase = fmaf(ab.x, jf, 255.5f + (float)PAD);
#pragma unroll
            for (int u = 0; u < 2; ++u) {
                float pyp = fmaf(ab.y, ifl[u], pybase);   // in [22,745] -> trunc == floor
                float cf  = truncf(pyp);
                float fy  = pyp - cf;
                int   c   = (int)cf;
                float4 p0 = cb[c];
                float4 p1 = cb[c + 1];
                float w0  = 1.f - fy;
                acc[u][0] = fmaf(p1.x, fy, fmaf(p0.x, w0, acc[u][0]));
                acc[u][1] = fmaf(p1.y, fy, fmaf(p0.y, w0, acc[u][1]));
                acc[u][2] = fmaf(p1.z, fy, fmaf(p0.z, w0, acc[u][2]));
                acc[u][3] = fmaf(p1.w, fy, fmaf(p0.w, w0, acc[u][3]));
            }
        }
        __syncthreads();   // reads of cur done; next DMA drained
        cur ^= 1;
    }

    const float s = (float)(3.14159265358979323846 / 720.0);
#pragma unroll
    for (int n = 0; n < 4; ++n)
#pragma unroll
        for (int u = 0; u < 2; ++u)
            out[(n * DD + (i0 + 4 * u)) * DD + j] = acc[u][n] * s;
}

extern "C" void kernel_launch(void* const* d_in, const int* in_sizes, int n_in,
                              void* d_out, int out_size, void* d_ws, size_t ws_size,
                              hipStream_t stream) {
    const float* radon = (const float*)d_in[0];
    const float* hG    = (const float*)d_in[1];
    // d_in[2] (t_y, 377MB) intentionally unused: recomputed analytically.
    float* out = (float*)d_out;
    float* ws  = (float*)d_ws;

    k_transpose<<<dim3(12, 16, 4), dim3(32, 8), 0, stream>>>(radon, ws);
    k_filter<<<WW, 256, 0, stream>>>(hG, ws);
    k_backproj<<<dim3(8, 64, 1), 256, 0, stream>>>(ws, out);
}

// Round 6
// 107.428 us; speedup vs baseline: 1.6169x; 1.6169x over previous
//
#include <hip/hip_runtime.h>

#define HH 512        // sinogram height (H_IN)
#define WW 360        // angles (W_IN)
#define NB 4          // batch
#define DD 512        // output D

#define NCHUNK 12
#define ANG_PER 30                          // 360/12

// ws layout in floats
#define OFF_TAB  0                          // float2 tab[360] -> 720 floats, pad to 1024
#define OFF_RT   1024                       // radonT [4][360][512] fp32
#define OFF_FILT (1024 + NB*WW*HH)          // filt4 [360][512][4] fp32
#define OFF_PART (OFF_FILT + WW*HH*NB)      // parts [12][4][512][512] fp32
#define CHUNK_ELEMS (NB*DD*DD)

#define PAD    128
#define COLS_N 768                          // 128 pad | 512 data | 128 pad (float4 rows)

#define GLOAD_LDS16(gp, lp)                                                   \
    __builtin_amdgcn_global_load_lds(                                         \
        (const __attribute__((address_space(1))) void*)(gp),                  \
        (__attribute__((address_space(3))) void*)(lp), 16, 0, 0)

// ---------------- K0: transpose radon[n][h][w] -> radonT[n][w][h] ----------------
__global__ __launch_bounds__(256) void k_transpose(const float* __restrict__ radon,
                                                   float* __restrict__ ws) {
    __shared__ float tile[32][33];
    int n  = blockIdx.z;
    int w0 = blockIdx.x * 32, h0 = blockIdx.y * 32;
    int x = threadIdx.x, y = threadIdx.y;  // 32 x 8
    const float* rn = radon + n * (HH * WW);
#pragma unroll
    for (int r = 0; r < 32; r += 8) {
        int h = h0 + y + r, w = w0 + x;
        tile[y + r][x] = (w < WW) ? rn[h * WW + w] : 0.f;
    }
    __syncthreads();
    float* rt = ws + OFF_RT + n * (WW * HH);
#pragma unroll
    for (int r = 0; r < 32; r += 8) {
        int w = w0 + y + r, h = h0 + x;
        if (w < WW) rt[w * HH + h] = tile[x][y + r];
    }
}

// ---------------- K1: circular ramp filter + fused angle table ----------------
// filt4[w][y][n] = sum_d radonT[n][w][(257+y+d)&511] * hG[d]
__global__ __launch_bounds__(256) void k_filter(const float* __restrict__ hG,
                                                float* __restrict__ ws) {
    __shared__ float r2[NB][1024];          // r2[n][i] = col[(i+257)&511]
    int wA  = blockIdx.x;
    int tid = threadIdx.x;

    if (tid == 0) {                          // angle table (double trig, validated)
        double th = (3.14159265358979323846 / 180.0) * (0.5 * (double)wA);
        double c = cos(th), s = sin(th);
        float2 ab;
        ab.x = (float)(c * (255.5 / 256.0));
        ab.y = (float)(-s * (255.5 / 256.0));
        ((float2*)(ws + OFF_TAB))[wA] = ab;
    }

    const float* rt = ws + OFF_RT;
    for (int t = tid; t < NB * 1024; t += 256) {
        int n = t >> 10, i = t & 1023;
        r2[n][i] = rt[(n * WW + wA) * HH + ((i + 257) & 511)];
    }
    __syncthreads();

    int n = tid >> 6, lane = tid & 63, y0 = lane << 3;   // 8 consecutive y per thread
    float acc[8] = {0, 0, 0, 0, 0, 0, 0, 0};
    const float* rr = &r2[n][y0];
    float4 Wr0 = *(const float4*)(rr + 0);
    float4 Wr1 = *(const float4*)(rr + 4);
    float4 Wr2 = *(const float4*)(rr + 8);
    float4 Wr3 = *(const float4*)(rr + 12);

    for (int d = 0; d < 512; d += 8) {
        float hg[8];
#pragma unroll
        for (int q = 0; q < 8; ++q) hg[q] = hG[d + q];   // uniform -> s_load
        float wf[16] = {Wr0.x, Wr0.y, Wr0.z, Wr0.w, Wr1.x, Wr1.y, Wr1.z, Wr1.w,
                        Wr2.x, Wr2.y, Wr2.z, Wr2.w, Wr3.x, Wr3.y, Wr3.z, Wr3.w};
#pragma unroll
        for (int du = 0; du < 8; ++du)
#pragma unroll
            for (int u = 0; u < 8; ++u)
                acc[u] = fmaf(wf[du + u], hg[du], acc[u]);
        if (d < 504) {
            Wr0 = Wr2; Wr1 = Wr3;
            Wr2 = *(const float4*)(rr + d + 16);
            Wr3 = *(const float4*)(rr + d + 20);
        }
    }
    float* filt = ws + OFF_FILT;
#pragma unroll
    for (int u = 0; u < 8; ++u)
        filt[(wA * HH + y0 + u) * NB + n] = acc[u];
}

// ---------------- K2: backprojection (12 angle-chunks, 6 blocks/CU) ----------------
__global__ __launch_bounds__(256, 6) void k_backproj(const float* __restrict__ ws,
                                                     float* __restrict__ parts) {
    __shared__ float4 cols[2][COLS_N];
    const int tid   = threadIdx.x;
    const int lane  = tid & 63;
    const int ithr  = tid >> 6;                        // 0..3
    const int j     = blockIdx.x * 64 + lane;
    const int i0    = blockIdx.y * 32 + ithr;          // i = i0 + 4u, u<8
    const int chunk = blockIdx.z;

    {   // zero pad regions only (never overlaps DMA region)
        int b = tid >> 7, r = tid & 127;
        float4 z = make_float4(0.f, 0.f, 0.f, 0.f);
        cols[b][r]            = z;                     // low pad  [0,128)
        cols[b][PAD + HH + r] = z;                     // high pad [640,768)
    }

    const float2* tab = (const float2*)(ws + OFF_TAB);
    const float4* fd  = (const float4*)(ws + OFF_FILT);

    float acc[8][4];
#pragma unroll
    for (int u = 0; u < 8; ++u)
#pragma unroll
        for (int n = 0; n < 4; ++n) acc[u][n] = 0.f;

    float jf = (float)(j - 256);
    float ifl[8];
#pragma unroll
    for (int u = 0; u < 8; ++u) ifl[u] = (float)(i0 + 4 * u - 256);

    const int wbeg = chunk * ANG_PER;
    {   // prologue: stage angle wbeg into buf 0 (512 x 16B = 8KB)
        const float4* src = fd + (size_t)wbeg * HH;
#pragma unroll
        for (int c = 0; c < 2; ++c) {
            int idx = tid + c * 256;
            GLOAD_LDS16(src + idx, &cols[0][PAD + idx]);
        }
    }
    __syncthreads();   // drains vmcnt(0): DMA + pad zeros visible

    int cur = 0;
    for (int k = 0; k < ANG_PER; ++k) {
        const int w = wbeg + k;
        if (k + 1 < ANG_PER) {                         // stage next angle into other buf
            const float4* src = fd + (size_t)(w + 1) * HH;
            float4* dst = &cols[cur ^ 1][PAD];
#pragma unroll
            for (int c = 0; c < 2; ++c) {
                int idx = tid + c * 256;
                GLOAD_LDS16(src + idx, dst + idx);
            }
        }

        float2 ab = tab[w];
        float pybase = fmaf(ab.x, jf, 255.5f + (float)PAD);
        const float4* cb = cols[cur];
#pragma unroll
        for (int u = 0; u < 8; ++u) {
            float pyp = fmaf(ab.y, ifl[u], pybase);    // in [22,745] -> trunc == floor
            float cf  = truncf(pyp);
            float fy  = pyp - cf;
            int   c   = (int)cf;
            float4 p0 = cb[c];
            float4 p1 = cb[c + 1];
            float w0  = 1.f - fy;
            acc[u][0] = fmaf(p1.x, fy, fmaf(p0.x, w0, acc[u][0]));
            acc[u][1] = fmaf(p1.y, fy, fmaf(p0.y, w0, acc[u][1]));
            acc[u][2] = fmaf(p1.z, fy, fmaf(p0.z, w0, acc[u][2]));
            acc[u][3] = fmaf(p1.w, fy, fmaf(p0.w, w0, acc[u][3]));
        }
        __syncthreads();   // reads of cur done; next DMA drained
        cur ^= 1;
    }

    float* part = parts + (size_t)chunk * CHUNK_ELEMS;
#pragma unroll
    for (int n = 0; n < 4; ++n)
#pragma unroll
        for (int u = 0; u < 8; ++u)
            part[(n * DD + (i0 + 4 * u)) * DD + j] = acc[u][n];
}

// ---------------- K3: reduce 12 chunks + scale (float4) ----------------
__global__ __launch_bounds__(256) void k_reduce(float* __restrict__ out,
                                                const float* __restrict__ ws) {
    int t = blockIdx.x * 256 + threadIdx.x;            // 262144 float4
    const float4* p = (const float4*)(ws + OFF_PART);
    const int C4 = CHUNK_ELEMS / 4;
    float4 a = p[t];
#pragma unroll
    for (int c = 1; c < NCHUNK; ++c) {
        float4 b = p[t + c * C4];
        a.x += b.x; a.y += b.y; a.z += b.z; a.w += b.w;
    }
    const float s = (float)(3.14159265358979323846 / 720.0);
    float4 r;
    r.x = a.x * s; r.y = a.y * s; r.z = a.z * s; r.w = a.w * s;
    ((float4*)out)[t] = r;
}

extern "C" void kernel_launch(void* const* d_in, const int* in_sizes, int n_in,
                              void* d_out, int out_size, void* d_ws, size_t ws_size,
                              hipStream_t stream) {
    const float* radon = (const float*)d_in[0];
    const float* hG    = (const float*)d_in[1];
    // d_in[2] (t_y, 377MB) intentionally unused: recomputed analytically.
    float* out = (float*)d_out;
    float* ws  = (float*)d_ws;

    k_transpose<<<dim3(12, 16, 4), dim3(32, 8), 0, stream>>>(radon, ws);
    k_filter<<<WW, 256, 0, stream>>>(hG, ws);
    k_backproj<<<dim3(8, 16, NCHUNK), 256, 0, stream>>>(ws, ws + OFF_PART);
    k_reduce<<<1024, 256, 0, stream>>>(out, ws);
}